// Round 1
// baseline (151.068 us; speedup 1.0000x reference)
//
#include <hip/hip_runtime.h>

#define BB 8
#define HH 256
#define LL 4096
#define DDIM 32
#define CLEN 64
#define NCHUNK 64
#define GD 8      // d's per thread
#define UPAD 68   // LDS row stride for u (64 + 4 pad, keeps 16B alignment)

// One block per (b,h). Chunked parallel scan over the 32-state complex
// linear recurrence  z_d[t] = r_d * z_d[t-1] + w_d * u[t],
// y[t] = sum_d Re(z_d[t]) + D_h * u[t].  Init term v_d * r^t folded into
// z[-1] = v/(w*r) (exact for any w != 0).
__global__ __launch_bounds__(256) void s4_scan_kernel(
    const float* __restrict__ u,      // (B,H,L)
    const float* __restrict__ theta,  // (1,H,DD)
    const float* __restrict__ a,      // (1,H,DD), already negative real part
    const float* __restrict__ Dp,     // (1,H)
    const float* __restrict__ b_p,    // (1,H,DD)
    const float* __restrict__ c_p,    // (1,H,DD)
    const float* __restrict__ x0,     // (1,H,DD)
    float* __restrict__ out)          // (B,H,L)
{
    const int tid = threadIdx.x;
    const int c   = tid >> 2;          // chunk index 0..63
    const int dg  = tid & 3;           // d-group 0..3
    const int bh  = blockIdx.x;
    const int h   = bh & (HH - 1);
    const float T = 1.0f / (LL - 1);

    __shared__ __align__(16) float u_s[NCHUNK * UPAD];
    __shared__ __align__(16) float Es[NCHUNK * DDIM * 2];
    __shared__ float Ar_s[DDIM], Ai_s[DDIM], z0r_s[DDIM], z0i_s[DDIM];

    // ---- per-thread constants for my 8 d's ----
    float rr[GD], ri[GD], wr[GD], wi[GD];
    const int dbase = dg * GD;
    const float Dh = Dp[h];

    #pragma unroll
    for (int j = 0; j < GD; ++j) {
        const int d  = dbase + j;
        const float lr = a[h * DDIM + d];       // = -|a| (a is already negative)
        const float li = theta[h * DDIM + d];
        float sn, cs;
        sincosf(li * T, &sn, &cs);
        const float er = expf(lr * T);
        const float Rr = er * cs, Ri = er * sn;  // r = exp(ls*T)
        // term0 = (r - 1)/ls
        const float den = lr * lr + li * li;     // |lr| >= 1, never ~0
        const float t0r = ((Rr - 1.f) * lr + Ri * li) / den;
        const float t0i = (Ri * lr - (Rr - 1.f) * li) / den;
        const float q   = b_p[h * DDIM + d] * c_p[h * DDIM + d];
        float wre = 2.f * q * t0r, wim = 2.f * q * t0i;
        // guard: w==0 would break the init fold; clamp is exact for the
        // init reconstruction, conv-coefficient error <= 1e-12 * |s| ~ 1e-10
        if (wre * wre + wim * wim < 1e-24f) { wre = 1e-12f; wim = 0.f; }
        rr[j] = Rr; ri[j] = Ri; wr[j] = wre; wi[j] = wim;
        if (c == 0) {   // tids 0..3 cover all 32 d's
            // A = r^CLEN via 6 squarings
            float pr = Rr, pi = Ri;
            #pragma unroll
            for (int s = 0; s < 6; ++s) {
                float nr = pr * pr - pi * pi;
                float ni = 2.f * pr * pi;
                pr = nr; pi = ni;
            }
            Ar_s[d] = pr; Ai_s[d] = pi;
            // z0 = v / (w * r),  v = 4T c_p x0 (real)
            const float v  = 4.f * T * c_p[h * DDIM + d] * x0[h * DDIM + d];
            const float cr = wre * Rr - wim * Ri;
            const float ci = wre * Ri + wim * Rr;
            const float cm = cr * cr + ci * ci;
            z0r_s[d] =  v * cr / cm;
            z0i_s[d] = -v * ci / cm;
        }
    }

    // ---- stage u into LDS (coalesced float4) ----
    const float* up = u + ((size_t)bh << 12);
    #pragma unroll
    for (int jj = 0; jj < 4; ++jj) {
        const int v4 = tid + jj * 256;            // float4 index 0..1023
        const float4 val = ((const float4*)up)[v4];
        const int t0 = v4 << 2;
        *(float4*)&u_s[(t0 >> 6) * UPAD + (t0 & 63)] = val;
    }
    __syncthreads();

    // ---- phase 1: local chunk recurrence, zero init -> end states E ----
    float zr[GD], zi[GD];
    #pragma unroll
    for (int j = 0; j < GD; ++j) { zr[j] = 0.f; zi[j] = 0.f; }
    const float* urow = &u_s[c * UPAD];
    for (int i0 = 0; i0 < CLEN; i0 += 4) {
        const float4 uu = *(const float4*)&urow[i0];
        const float uk[4] = {uu.x, uu.y, uu.z, uu.w};
        #pragma unroll
        for (int k = 0; k < 4; ++k) {
            #pragma unroll
            for (int j = 0; j < GD; ++j) {
                const float nr = fmaf(rr[j], zr[j], fmaf(-ri[j], zi[j], uk[k]));
                const float ni = fmaf(ri[j], zr[j], rr[j] * zi[j]);
                zr[j] = nr; zi[j] = ni;
            }
        }
    }
    {
        float* ep = &Es[(c * DDIM + dbase) * 2];
        #pragma unroll
        for (int j = 0; j < GD; j += 2)
            *(float4*)&ep[2 * j] = make_float4(zr[j], zi[j], zr[j + 1], zi[j + 1]);
    }
    __syncthreads();

    // ---- scan: 32 threads, sequential over 64 chunks; in-place E -> S ----
    if (tid < DDIM) {
        const int d = tid;
        float cr = z0r_s[d], ci = z0i_s[d];       // z[-1]
        const float ar = Ar_s[d], ai = Ai_s[d];
        for (int cc = 0; cc < NCHUNK; ++cc) {
            float* ep = &Es[(cc * DDIM + d) * 2];
            const float ex = ep[0], ey = ep[1];
            ep[0] = cr; ep[1] = ci;               // incoming state S_cc
            const float nr = fmaf(ar, cr, fmaf(-ai, ci, ex));
            const float ni = fmaf(ai, cr, fmaf(ar, ci, ey));
            cr = nr; ci = ni;
        }
    }
    __syncthreads();

    // ---- phase 2: re-run with true incoming state, emit y ----
    {
        const float* ep = &Es[(c * DDIM + dbase) * 2];
        #pragma unroll
        for (int j = 0; j < GD; ++j) { zr[j] = ep[2 * j]; zi[j] = ep[2 * j + 1]; }
    }
    float* orow = out + ((size_t)bh << 12) + c * CLEN;
    const int b0 = dg & 1, b1 = dg >> 1;
    for (int i0 = 0; i0 < CLEN; i0 += 4) {
        const float4 uu = *(const float4*)&urow[i0];
        const float uk[4] = {uu.x, uu.y, uu.z, uu.w};
        float ps[4];
        #pragma unroll
        for (int k = 0; k < 4; ++k) {
            float acc = 0.f;
            #pragma unroll
            for (int j = 0; j < GD; ++j) {
                const float nr = fmaf(rr[j], zr[j], fmaf(-ri[j], zi[j], uk[k]));
                const float ni = fmaf(ri[j], zr[j], rr[j] * zi[j]);
                zr[j] = nr; zi[j] = ni;
                acc = fmaf(wr[j], nr, acc);
                acc = fmaf(-wi[j], ni, acc);
            }
            ps[k] = acc;
        }
        // 4x4 butterfly transpose-reduce across the 4 dg lanes:
        // lane dg ends with the full sum for t = c*CLEN + i0 + dg
        const float keep0 = b0 ? ps[1] : ps[0];
        const float send0 = b0 ? ps[0] : ps[1];
        const float keep1 = b0 ? ps[3] : ps[2];
        const float send1 = b0 ? ps[2] : ps[3];
        const float s0 = keep0 + __shfl_xor(send0, 1);
        const float s1 = keep1 + __shfl_xor(send1, 1);
        const float tosend = b1 ? s0 : s1;
        float fin = (b1 ? s1 : s0) + __shfl_xor(tosend, 2);
        const float uD = b1 ? (b0 ? uk[3] : uk[2]) : (b0 ? uk[1] : uk[0]);
        fin = fmaf(Dh, uD, fin);
        orow[i0 + dg] = fin;
    }
}

extern "C" void kernel_launch(void* const* d_in, const int* in_sizes, int n_in,
                              void* d_out, int out_size, void* d_ws, size_t ws_size,
                              hipStream_t stream) {
    const float* u     = (const float*)d_in[0];
    const float* theta = (const float*)d_in[1];
    const float* a     = (const float*)d_in[2];
    const float* Dp    = (const float*)d_in[3];
    const float* b_p   = (const float*)d_in[4];
    const float* c_p   = (const float*)d_in[5];
    const float* x0    = (const float*)d_in[6];
    float* out = (float*)d_out;
    hipLaunchKernelGGL(s4_scan_kernel, dim3(BB * HH), dim3(256), 0, stream,
                       u, theta, a, Dp, b_p, c_p, x0, out);
}

// Round 2
// 110.801 us; speedup vs baseline: 1.3634x; 1.3634x over previous
//
#include <hip/hip_runtime.h>

#define BB 8
#define HH 256
#define LL 4096
#define DD2 32
#define STR 72          // bf16 matrix row stride (64 + 8 pad, keeps 16B align, 2-way-max read conflicts)
#define ESTR 65         // fp32 E-state row stride (conflict-free column walks)

typedef __attribute__((ext_vector_type(8))) short short8;   // 8 bf16 = one MFMA A/B frag
typedef __attribute__((ext_vector_type(4))) float f32x4;    // MFMA C/D frag

static __device__ inline unsigned short f2bf(float x) {
    union { float f; unsigned u; } v; v.f = x;
    unsigned r = v.u + 0x7fffu + ((v.u >> 16) & 1u);   // RNE
    return (unsigned short)(r >> 16);
}

// complex mul: (or,oi) = (ar,ai)*(br,bi)
#define CMUL(or_, oi_, ar_, ai_, br_, bi_) do { \
    float _tr = fmaf((ar_), (br_), -(ai_) * (bi_)); \
    float _ti = fmaf((ar_), (bi_), (ai_) * (br_)); \
    (or_) = _tr; (oi_) = _ti; } while (0)

__global__ __launch_bounds__(256) void s4_mfma_kernel(
    const float* __restrict__ u,      // (B,H,L)
    const float* __restrict__ theta,  // (1,H,32)
    const float* __restrict__ a,      // (1,H,32) negative real parts
    const float* __restrict__ Dp,     // (1,H)
    const float* __restrict__ b_p,    // (1,H,32)
    const float* __restrict__ c_p,    // (1,H,32)
    const float* __restrict__ x0,     // (1,H,32)
    float* __restrict__ out)          // (B,H,L)
{
    const int tid = threadIdx.x;
    const int bh  = blockIdx.x;
    const int hh  = bh & (HH - 1);
    const float T = 1.0f / (LL - 1);

    // LDS map (shorts). Us[c][tau] / Hs[t][tau] / Ps[dd][tau] / Rs[k][dd]: 64 rows x STR.
    // Aliases: Qs[c][dd] <- Us (after matmuls 1,2);  Es fp32 [dd][ESTR] <- Hs..Ps (after matmul 1,2).
    __shared__ __align__(16) short lds[18432 + 128];
    short* Us = lds;
    short* Hs = lds + 4608;
    short* Ps = lds + 9216;
    short* Rs = lds + 13824;
    float* h_s = (float*)&lds[18432];     // h[0..63]
    float* Es  = (float*)&lds[4608];      // 64 x 65 fp32, fits in Hs+Ps region

    // ---- stage u -> Us[c][tau] (bf16) ----
    const float* up = u + ((size_t)bh << 12);
    #pragma unroll
    for (int jj = 0; jj < 4; ++jj) {
        const int v  = tid + (jj << 8);          // float4 index 0..1023
        const float4 val = ((const float4*)up)[v];
        const int c  = v >> 4;
        const int t0 = (v & 15) << 2;
        uint2 pk;
        pk.x = (unsigned)f2bf(val.x) | ((unsigned)f2bf(val.y) << 16);
        pk.y = (unsigned)f2bf(val.z) | ((unsigned)f2bf(val.w) << 16);
        *(uint2*)&Us[c * STR + t0] = pk;
    }

    // ---- per-d constants (thread = (d, kb)) ----
    const int d  = tid & 31;
    const int kb = tid >> 5;                     // 0..7: k-block of 8
    const float lr = a[hh * DD2 + d];            // already negative
    const float li = theta[hh * DD2 + d];
    float sn, cS;
    sincosf(li * T, &sn, &cS);
    const float er = expf(lr * T);
    const float Rr = er * cS, Ri = er * sn;      // r = exp(ls*T)
    const float den = lr * lr + li * li;
    const float t0r = ((Rr - 1.f) * lr + Ri * li) / den;
    const float t0i = (Ri * lr - (Rr - 1.f) * li) / den;
    const float qq  = b_p[hh * DD2 + d] * c_p[hh * DD2 + d];
    const float wre = 2.f * qq * t0r, wim = 2.f * qq * t0i;   // w
    const float vv  = 4.f * T * c_p[hh * DD2 + d] * x0[hh * DD2 + d];  // init amplitude (real)

    // powers r^2,4,8,16,32
    float r2r, r2i, r4r, r4i, r8r, r8i, r16r, r16i, r32r, r32i;
    CMUL(r2r, r2i, Rr, Ri, Rr, Ri);
    CMUL(r4r, r4i, r2r, r2i, r2r, r2i);
    CMUL(r8r, r8i, r4r, r4i, r4r, r4i);
    CMUL(r16r, r16i, r8r, r8i, r8r, r8i);
    CMUL(r32r, r32i, r16r, r16i, r16r, r16i);

    // p = r^(8*kb)
    float pr = 1.f, pi = 0.f;
    if (kb & 1) CMUL(pr, pi, pr, pi, r8r, r8i);
    if (kb & 2) CMUL(pr, pi, pr, pi, r16r, r16i);
    if (kb & 4) CMUL(pr, pi, pr, pi, r32r, r32i);

    // fill Rs[k][dd], Ps[dd][63-k], and h_s[k] (butterfly over d within half-wave)
    #pragma unroll
    for (int k8 = 0; k8 < 8; ++k8) {
        const int k = (kb << 3) + k8;
        Rs[k * STR + d]       = (short)f2bf(pr);
        Rs[k * STR + 32 + d]  = (short)f2bf(-pi);
        Ps[d * STR + (63 - k)]        = (short)f2bf(pr);
        Ps[(32 + d) * STR + (63 - k)] = (short)f2bf(pi);
        float hk = fmaf(wre, pr, -wim * pi);     // Re(w * r^k)
        hk += __shfl_xor(hk, 1);
        hk += __shfl_xor(hk, 2);
        hk += __shfl_xor(hk, 4);
        hk += __shfl_xor(hk, 8);
        hk += __shfl_xor(hk, 16);
        if (d == 0) h_s[k] = hk;
        CMUL(pr, pi, pr, pi, Rr, Ri);
    }
    __syncthreads();

    // ---- build Toeplitz Hs[t][tau] = h[t-tau] (t>=tau) ----
    {
        const int t  = tid >> 2;
        const int tb = (tid & 3) << 4;
        #pragma unroll
        for (int g = 0; g < 4; ++g) {
            const int tau0 = tb + (g << 2);
            unsigned short e[4];
            #pragma unroll
            for (int i = 0; i < 4; ++i) {
                const int dt = t - (tau0 + i);
                e[i] = (dt >= 0) ? f2bf(h_s[dt]) : (unsigned short)0;
            }
            uint2 pk;
            pk.x = (unsigned)e[0] | ((unsigned)e[1] << 16);
            pk.y = (unsigned)e[2] | ((unsigned)e[3] << 16);
            *(uint2*)&Hs[t * STR + tau0] = pk;
        }
    }
    __syncthreads();

    // ---- matmuls 1 (Y1 = H x U) and 2 (E = P x U), shared B-frags ----
    const int ln   = tid & 63;
    const int m0   = (tid >> 6) << 4;     // wave's 16-row output slice
    const int rowi = ln & 15;
    const int quad = ln >> 4;
    f32x4 accY[4], accE[4];
    #pragma unroll
    for (int nt = 0; nt < 4; ++nt) {
        accY[nt] = (f32x4){0.f, 0.f, 0.f, 0.f};
        accE[nt] = (f32x4){0.f, 0.f, 0.f, 0.f};
    }
    #pragma unroll
    for (int k0 = 0; k0 < 64; k0 += 32) {
        const short8 aH = *(const short8*)&Hs[(m0 + rowi) * STR + k0 + (quad << 3)];
        const short8 aP = *(const short8*)&Ps[(m0 + rowi) * STR + k0 + (quad << 3)];
        #pragma unroll
        for (int nt = 0; nt < 4; ++nt) {
            const short8 bU = *(const short8*)&Us[((nt << 4) + rowi) * STR + k0 + (quad << 3)];
            accY[nt] = __builtin_amdgcn_mfma_f32_16x16x32_bf16(aH, bU, accY[nt], 0, 0, 0);
            accE[nt] = __builtin_amdgcn_mfma_f32_16x16x32_bf16(aP, bU, accE[nt], 0, 0, 0);
        }
    }
    __syncthreads();   // everyone done reading Hs/Ps (Es aliases them)

    // ---- write E frags -> Es[dd][c] fp32 ----
    #pragma unroll
    for (int nt = 0; nt < 4; ++nt)
        #pragma unroll
        for (int i = 0; i < 4; ++i)
            Es[(m0 + (quad << 2) + i) * ESTR + (nt << 4) + rowi] = accE[nt][i];
    __syncthreads();

    // ---- sequential chunk scan (32 threads), write Qs[c][dd] (aliases Us) ----
    if (tid < 32) {
        float Sr = 0.f, Si = 0.f;          // state entering chunk c
        float Gr = vv, Gi = 0.f;           // v * r^(64c)
        float Ar, Ai;                      // A = r^64
        CMUL(Ar, Ai, r32r, r32i, r32r, r32i);
        float wrrR, wrrI;                  // w * r
        CMUL(wrrR, wrrI, wre, wim, Rr, Ri);
        short* Qs = Us;
        for (int c = 0; c < 64; ++c) {
            const float Er = Es[d * ESTR + c];
            const float Ei = Es[(32 + d) * ESTR + c];
            const float Qr = fmaf(wrrR, Sr, fmaf(-wrrI, Si, Gr));
            const float Qi = fmaf(wrrR, Si, fmaf(wrrI, Sr, Gi));
            Qs[c * STR + d]      = (short)f2bf(Qr);
            Qs[c * STR + 32 + d] = (short)f2bf(Qi);
            const float nSr = fmaf(Ar, Sr, fmaf(-Ai, Si, Er));
            const float nSi = fmaf(Ar, Si, fmaf(Ai, Sr, Ei));
            Sr = nSr; Si = nSi;
            float nGr, nGi;
            CMUL(nGr, nGi, Ar, Ai, Gr, Gi);
            Gr = nGr; Gi = nGi;
        }
    }
    __syncthreads();

    // ---- matmul 3: Y += R x Q (same accumulators) ----
    #pragma unroll
    for (int k0 = 0; k0 < 64; k0 += 32) {
        const short8 aR = *(const short8*)&Rs[(m0 + rowi) * STR + k0 + (quad << 3)];
        #pragma unroll
        for (int nt = 0; nt < 4; ++nt) {
            const short8 bQ = *(const short8*)&Us[((nt << 4) + rowi) * STR + k0 + (quad << 3)];
            accY[nt] = __builtin_amdgcn_mfma_f32_16x16x32_bf16(aR, bQ, accY[nt], 0, 0, 0);
        }
    }

    // ---- epilogue: += D*u (fp32 from global, L2-hot), direct 16B stores ----
    const float Dh = Dp[hh];
    float* op = out + ((size_t)bh << 12);
    #pragma unroll
    for (int nt = 0; nt < 4; ++nt) {
        const int c    = (nt << 4) + rowi;
        const int toff = m0 + (quad << 2);
        const float4 uu = *(const float4*)&up[c * 64 + toff];
        float4 res;
        res.x = fmaf(Dh, uu.x, accY[nt][0]);
        res.y = fmaf(Dh, uu.y, accY[nt][1]);
        res.z = fmaf(Dh, uu.z, accY[nt][2]);
        res.w = fmaf(Dh, uu.w, accY[nt][3]);
        *(float4*)&op[c * 64 + toff] = res;
    }
}

extern "C" void kernel_launch(void* const* d_in, const int* in_sizes, int n_in,
                              void* d_out, int out_size, void* d_ws, size_t ws_size,
                              hipStream_t stream) {
    const float* u     = (const float*)d_in[0];
    const float* theta = (const float*)d_in[1];
    const float* a     = (const float*)d_in[2];
    const float* Dp    = (const float*)d_in[3];
    const float* b_p   = (const float*)d_in[4];
    const float* c_p   = (const float*)d_in[5];
    const float* x0    = (const float*)d_in[6];
    float* out = (float*)d_out;
    hipLaunchKernelGGL(s4_mfma_kernel, dim3(BB * HH), dim3(256), 0, stream,
                       u, theta, a, Dp, b_p, c_p, x0, out);
}

// Round 3
// 104.857 us; speedup vs baseline: 1.4407x; 1.0567x over previous
//
#include <hip/hip_runtime.h>

#define BB 8
#define HH 256
#define LL 4096
#define DD2 32
#define STR 72          // bf16 matrix row stride (64 + 8 pad)
#define ESTRS 140       // Es (bf16 pair-packed) row stride in shorts: 32 rows x 140
#define SEGSTR 18       // Seg row stride in floats

typedef __attribute__((ext_vector_type(8))) short short8;   // 8 bf16 = MFMA A/B frag
typedef __attribute__((ext_vector_type(4))) float f32x4;    // MFMA C/D frag

static __device__ inline unsigned short f2bf(float x) {
    union { float f; unsigned u; } v; v.f = x;
    unsigned r = v.u + 0x7fffu + ((v.u >> 16) & 1u);   // RNE
    return (unsigned short)(r >> 16);
}
static __device__ inline float bf2f(unsigned us) {
    union { unsigned u; float f; } v; v.u = us << 16; return v.f;
}

#define CMUL(or_, oi_, ar_, ai_, br_, bi_) do { \
    float _tr = fmaf((ar_), (br_), -(ai_) * (bi_)); \
    float _ti = fmaf((ar_), (bi_), (ai_) * (br_)); \
    (or_) = _tr; (oi_) = _ti; } while (0)

__global__ __launch_bounds__(256, 5) void s4_mfma_kernel(
    const float* __restrict__ u,      // (B,H,L)
    const float* __restrict__ theta,  // (1,H,32)
    const float* __restrict__ a,      // (1,H,32) negative real parts
    const float* __restrict__ Dp,     // (1,H)
    const float* __restrict__ b_p,    // (1,H,32)
    const float* __restrict__ c_p,    // (1,H,32)
    const float* __restrict__ x0,     // (1,H,32)
    float* __restrict__ out)          // (B,H,L)
{
    const int tid = threadIdx.x;
    const int bh  = blockIdx.x;
    const int hh  = bh & (HH - 1);
    const float T = 1.0f / (LL - 1);

    // LDS (shorts), 30208 B total -> 5 blocks/CU:
    //  Us [0,4608)      : u bf16 [c][tau]  -> later Qs [c][dd]
    //  X1 [4608,9216)   : Hs [t][tau]      -> later Es bf16 [d][2c+im] stride 140
    //  X2 [9216,13824)  : Ps [dd][tau]     -> later Rs [k][dd]
    //  h_s [13824,13952): 64 f32
    //  Seg [13952,15104): 32 x 18 f32 (complex segment sums)
    __shared__ __align__(16) short lds[15104];
    short* Us  = lds;
    short* Hs  = lds + 4608;
    short* EsS = lds + 4608;
    short* Ps  = lds + 9216;
    short* Rs  = lds + 9216;
    float* h_s = (float*)&lds[13824];
    float* SegF = (float*)&lds[13952];

    // ---- stage u -> Us[c][tau] (bf16) ----
    const float* up = u + ((size_t)bh << 12);
    #pragma unroll
    for (int jj = 0; jj < 4; ++jj) {
        const int v  = tid + (jj << 8);
        const float4 val = ((const float4*)up)[v];
        const int c  = v >> 4;
        const int t0 = (v & 15) << 2;
        uint2 pk;
        pk.x = (unsigned)f2bf(val.x) | ((unsigned)f2bf(val.y) << 16);
        pk.y = (unsigned)f2bf(val.z) | ((unsigned)f2bf(val.w) << 16);
        *(uint2*)&Us[c * STR + t0] = pk;
    }

    // ---- per-thread constants: thread = (d = tid&31, kb = tid>>5) ----
    const int d  = tid & 31;
    const int kb = tid >> 5;                 // also the scan segment index g
    const float lr = a[hh * DD2 + d];
    const float li = theta[hh * DD2 + d];
    float sn, cS;
    sincosf(li * T, &sn, &cS);
    const float er = expf(lr * T);
    const float Rr = er * cS, Ri = er * sn;  // r = exp(ls*T)
    const float den = lr * lr + li * li;
    const float t0r = ((Rr - 1.f) * lr + Ri * li) / den;
    const float t0i = (Ri * lr - (Rr - 1.f) * li) / den;
    const float qq  = b_p[hh * DD2 + d] * c_p[hh * DD2 + d];
    const float wre = 2.f * qq * t0r, wim = 2.f * qq * t0i;   // w
    const float vv  = 4.f * T * c_p[hh * DD2 + d] * x0[hh * DD2 + d];

    // powers r^2..r^32 (r8/r16/r32 retained for Rs rebuild + scan)
    float r2r, r2i, r4r, r4i, r8r, r8i, r16r, r16i, r32r, r32i;
    CMUL(r2r, r2i, Rr, Ri, Rr, Ri);
    CMUL(r4r, r4i, r2r, r2i, r2r, r2i);
    CMUL(r8r, r8i, r4r, r4i, r4r, r4i);
    CMUL(r16r, r16i, r8r, r8i, r8r, r8i);
    CMUL(r32r, r32i, r16r, r16i, r16r, r16i);

    // ---- build Ps[dd][63-k] and h_s[k] ----
    {
        float pr = 1.f, pi = 0.f;            // r^(8*kb)
        if (kb & 1) CMUL(pr, pi, pr, pi, r8r, r8i);
        if (kb & 2) CMUL(pr, pi, pr, pi, r16r, r16i);
        if (kb & 4) CMUL(pr, pi, pr, pi, r32r, r32i);
        #pragma unroll
        for (int k8 = 0; k8 < 8; ++k8) {
            const int k = (kb << 3) + k8;
            Ps[d * STR + (63 - k)]        = (short)f2bf(pr);
            Ps[(32 + d) * STR + (63 - k)] = (short)f2bf(pi);
            float hk = fmaf(wre, pr, -wim * pi);     // Re(w * r^k)
            hk += __shfl_xor(hk, 1);
            hk += __shfl_xor(hk, 2);
            hk += __shfl_xor(hk, 4);
            hk += __shfl_xor(hk, 8);
            hk += __shfl_xor(hk, 16);
            if (d == 0) h_s[k] = hk;
            CMUL(pr, pi, pr, pi, Rr, Ri);
        }
    }
    __syncthreads();                                  // b1: Us, Ps, h_s ready

    // ---- build Toeplitz Hs[t][tau] = h[t-tau] ----
    {
        const int t  = tid >> 2;
        const int tb = (tid & 3) << 4;
        #pragma unroll
        for (int g = 0; g < 4; ++g) {
            const int tau0 = tb + (g << 2);
            unsigned short e[4];
            #pragma unroll
            for (int i = 0; i < 4; ++i) {
                const int dt = t - (tau0 + i);
                e[i] = (dt >= 0) ? f2bf(h_s[dt]) : (unsigned short)0;
            }
            uint2 pk;
            pk.x = (unsigned)e[0] | ((unsigned)e[1] << 16);
            pk.y = (unsigned)e[2] | ((unsigned)e[3] << 16);
            *(uint2*)&Hs[t * STR + tau0] = pk;
        }
    }
    __syncthreads();                                  // b2: Hs ready

    // ---- fused matmuls: Y1 = H x U, E = P x U (shared B frags) ----
    const int ln   = tid & 63;
    const int m0   = (tid >> 6) << 4;
    const int rowi = ln & 15;
    const int quad = ln >> 4;
    f32x4 accY[4], accE[4];
    #pragma unroll
    for (int nt = 0; nt < 4; ++nt) {
        accY[nt] = (f32x4){0.f, 0.f, 0.f, 0.f};
        accE[nt] = (f32x4){0.f, 0.f, 0.f, 0.f};
    }
    #pragma unroll
    for (int k0 = 0; k0 < 64; k0 += 32) {
        const short8 aH = *(const short8*)&Hs[(m0 + rowi) * STR + k0 + (quad << 3)];
        const short8 aP = *(const short8*)&Ps[(m0 + rowi) * STR + k0 + (quad << 3)];
        #pragma unroll
        for (int nt = 0; nt < 4; ++nt) {
            const short8 bU = *(const short8*)&Us[((nt << 4) + rowi) * STR + k0 + (quad << 3)];
            accY[nt] = __builtin_amdgcn_mfma_f32_16x16x32_bf16(aH, bU, accY[nt], 0, 0, 0);
            accE[nt] = __builtin_amdgcn_mfma_f32_16x16x32_bf16(aP, bU, accE[nt], 0, 0, 0);
        }
    }
    __syncthreads();                                  // b3: Hs/Ps/Us free

    // ---- write E -> Es bf16 [d][2c+im]; rebuild Rs[k][dd] over Ps ----
    #pragma unroll
    for (int nt = 0; nt < 4; ++nt)
        #pragma unroll
        for (int i = 0; i < 4; ++i) {
            const int dd = m0 + (quad << 2) + i;
            EsS[(dd & 31) * ESTRS + (((nt << 4) + rowi) << 1) + (dd >> 5)] =
                (short)f2bf(accE[nt][i]);
        }
    {
        float pr = 1.f, pi = 0.f;            // r^(8*kb) again
        if (kb & 1) CMUL(pr, pi, pr, pi, r8r, r8i);
        if (kb & 2) CMUL(pr, pi, pr, pi, r16r, r16i);
        if (kb & 4) CMUL(pr, pi, pr, pi, r32r, r32i);
        #pragma unroll
        for (int k8 = 0; k8 < 8; ++k8) {
            const int k = (kb << 3) + k8;
            Rs[k * STR + d]      = (short)f2bf(pr);
            Rs[k * STR + 32 + d] = (short)f2bf(-pi);
            CMUL(pr, pi, pr, pi, Rr, Ri);
        }
    }
    __syncthreads();                                  // b4: Es, Rs ready

    // ---- blocked scan, all 256 threads: thread (d, g) owns chunks [8g,8g+8) ----
    const int g = kb;
    float Ar, Ai;                                     // A = r^64 (chunk step)
    CMUL(Ar, Ai, r32r, r32i, r32r, r32i);
    {   // phase a: local zero-init scan -> segment sum
        float Sr = 0.f, Si = 0.f;
        #pragma unroll
        for (int i = 0; i < 8; ++i) {
            const unsigned ee = *(const unsigned*)&EsS[d * ESTRS + (((g << 3) + i) << 1)];
            const float Er = bf2f(ee & 0xffffu), Ei = bf2f(ee >> 16);
            const float nr = fmaf(Ar, Sr, fmaf(-Ai, Si, Er));
            const float ni = fmaf(Ar, Si, fmaf(Ai, Sr, Ei));
            Sr = nr; Si = ni;
        }
        SegF[d * SEGSTR + (g << 1)]     = Sr;
        SegF[d * SEGSTR + (g << 1) + 1] = Si;
    }
    __syncthreads();                                  // b5: Seg ready

    {   // phase c: combine + emit Q (over Us region)
        float S8r, S8i, S16r, S16i, S32r, S32i;       // A^8, A^16, A^32
        float b1r, b1i, b2r, b2i;
        CMUL(b1r, b1i, Ar, Ai, Ar, Ai);               // r^128
        CMUL(b2r, b2i, b1r, b1i, b1r, b1i);           // r^256
        CMUL(S8r, S8i, b2r, b2i, b2r, b2i);           // r^512  = A^8
        CMUL(S16r, S16i, S8r, S8i, S8r, S8i);         // A^16
        CMUL(S32r, S32i, S16r, S16i, S16r, S16i);     // A^32
        // off = state entering segment g (Horner over earlier segments)
        float offr = 0.f, offi = 0.f;
        #pragma unroll
        for (int gp = 0; gp < 7; ++gp) {
            const float sr = SegF[d * SEGSTR + (gp << 1)];
            const float si = SegF[d * SEGSTR + (gp << 1) + 1];
            const float nr = fmaf(S8r, offr, fmaf(-S8i, offi, sr));
            const float ni = fmaf(S8r, offi, fmaf(S8i, offr, si));
            const bool take = gp < g;
            offr = take ? nr : offr;
            offi = take ? ni : offi;
        }
        // G = v * A^(8g)  (init term, exact — no clamp needed)
        float Gr = vv, Gi = 0.f;
        if (g & 1) { float nr, ni; CMUL(nr, ni, Gr, Gi, S8r, S8i);  Gr = nr; Gi = ni; }
        if (g & 2) { float nr, ni; CMUL(nr, ni, Gr, Gi, S16r, S16i); Gr = nr; Gi = ni; }
        if (g & 4) { float nr, ni; CMUL(nr, ni, Gr, Gi, S32r, S32i); Gr = nr; Gi = ni; }
        float wrrR, wrrI;                             // w * r
        CMUL(wrrR, wrrI, wre, wim, Rr, Ri);
        float Sr = offr, Si = offi;
        short* Qs = Us;
        #pragma unroll
        for (int i = 0; i < 8; ++i) {
            const int c = (g << 3) + i;
            const unsigned ee = *(const unsigned*)&EsS[d * ESTRS + (c << 1)];
            const float Er = bf2f(ee & 0xffffu), Ei = bf2f(ee >> 16);
            const float Qr = fmaf(wrrR, Sr, fmaf(-wrrI, Si, Gr));
            const float Qi = fmaf(wrrR, Si, fmaf(wrrI, Sr, Gi));
            Qs[c * STR + d]      = (short)f2bf(Qr);
            Qs[c * STR + 32 + d] = (short)f2bf(Qi);
            const float nr = fmaf(Ar, Sr, fmaf(-Ai, Si, Er));
            const float ni = fmaf(Ar, Si, fmaf(Ai, Sr, Ei));
            Sr = nr; Si = ni;
            float nGr, nGi;
            CMUL(nGr, nGi, Ar, Ai, Gr, Gi);
            Gr = nGr; Gi = nGi;
        }
    }
    __syncthreads();                                  // b6: Qs ready

    // ---- hoisted epilogue u loads (cover mm3 latency) ----
    float4 uu[4];
    #pragma unroll
    for (int nt = 0; nt < 4; ++nt)
        uu[nt] = *(const float4*)&up[((nt << 4) + rowi) * 64 + m0 + (quad << 2)];

    // ---- matmul 3: Y += R x Q ----
    #pragma unroll
    for (int k0 = 0; k0 < 64; k0 += 32) {
        const short8 aR = *(const short8*)&Rs[(m0 + rowi) * STR + k0 + (quad << 3)];
        #pragma unroll
        for (int nt = 0; nt < 4; ++nt) {
            const short8 bQ = *(const short8*)&Us[((nt << 4) + rowi) * STR + k0 + (quad << 3)];
            accY[nt] = __builtin_amdgcn_mfma_f32_16x16x32_bf16(aR, bQ, accY[nt], 0, 0, 0);
        }
    }

    // ---- epilogue: += D*u, direct float4 stores ----
    const float Dh = Dp[hh];
    float* op = out + ((size_t)bh << 12);
    #pragma unroll
    for (int nt = 0; nt < 4; ++nt) {
        const int c    = (nt << 4) + rowi;
        const int toff = m0 + (quad << 2);
        float4 res;
        res.x = fmaf(Dh, uu[nt].x, accY[nt][0]);
        res.y = fmaf(Dh, uu[nt].y, accY[nt][1]);
        res.z = fmaf(Dh, uu[nt].z, accY[nt][2]);
        res.w = fmaf(Dh, uu[nt].w, accY[nt][3]);
        *(float4*)&op[c * 64 + toff] = res;
    }
}

extern "C" void kernel_launch(void* const* d_in, const int* in_sizes, int n_in,
                              void* d_out, int out_size, void* d_ws, size_t ws_size,
                              hipStream_t stream) {
    const float* u     = (const float*)d_in[0];
    const float* theta = (const float*)d_in[1];
    const float* a     = (const float*)d_in[2];
    const float* Dp    = (const float*)d_in[3];
    const float* b_p   = (const float*)d_in[4];
    const float* c_p   = (const float*)d_in[5];
    const float* x0    = (const float*)d_in[6];
    float* out = (float*)d_out;
    hipLaunchKernelGGL(s4_mfma_kernel, dim3(BB * HH), dim3(256), 0, stream,
                       u, theta, a, Dp, b_p, c_p, x0, out);
}